// Round 16
// baseline (140.521 us; speedup 1.0000x reference)
//
#include <hip/hip_runtime.h>

constexpr int B = 8, N = 8192, S = 2048, D = 64, K = 16, C = 3 + D;
constexpr int G = 8;  // queries per wave

// Map float -> monotonically sortable unsigned (total order matches float <)
__device__ __forceinline__ unsigned sortable(float f) {
    unsigned u = __float_as_uint(f);
    unsigned mask = (unsigned)(((int)u) >> 31) | 0x80000000u;
    return u ^ mask;
}

// Wave-uniform load -> SGPR
__device__ __forceinline__ float uload(const float* p) {
    return __uint_as_float(__builtin_amdgcn_readfirstlane(__float_as_uint(*p)));
}

// Scalar reference-exact distance (fallback path): dot asc-FMA, d=(pn-2dot)+qn [R8]
__device__ __forceinline__ float make_d(float px, float py, float pz, float pnv,
                                        float qx, float qy, float qz, float qn) {
    float dot = __fmaf_rn(pz, qz, __fmaf_rn(py, qy, __fmul_rn(px, qx)));
    return __fadd_rn(__fsub_rn(pnv, __fmul_rn(2.0f, dot)), qn);
}

// EXACT v = pn - dot2; dot2 = fma(pz,q2z, fma(py,q2y, px*q2x)) == 2*dot bitwise
__device__ __forceinline__ float make_v(float px, float py, float pz, float pnv,
                                        float q2x, float q2y, float q2z) {
    float dot2 = __fmaf_rn(pz, q2z, __fmaf_rn(py, q2y, __fmul_rn(px, q2x)));
    return __fsub_rn(pnv, dot2);
}

// FUSED 3-FMA proxy: |vt - exact v| <= ~3e-5; used only with >= 1e-4 margins
__device__ __forceinline__ float make_vt(float px, float py, float pz, float pnv,
                                         float nq2x, float nq2y, float nq2z) {
    return __fmaf_rn(px, nq2x, __fmaf_rn(py, nq2y, __fmaf_rn(pz, nq2z, pnv)));
}

__device__ __forceinline__ float bitonic_sort64_f32(float v, int lane) {
#pragma unroll
    for (int k = 2; k <= 64; k <<= 1)
#pragma unroll
        for (int j = k >> 1; j > 0; j >>= 1) {
            float o = __shfl_xor(v, j, 64);
            bool keepmin = ((lane & k) == 0) == ((lane & j) == 0);
            float mn = fminf(v, o), mx = fmaxf(v, o);
            v = keepmin ? mn : mx;
        }
    return v;
}

__device__ __forceinline__ unsigned long long bitonic_sort64_u64(unsigned long long v, int lane) {
#pragma unroll
    for (int k = 2; k <= 64; k <<= 1)
#pragma unroll
        for (int j = k >> 1; j > 0; j >>= 1) {
            unsigned long long o = __shfl_xor(v, j, 64);
            bool keepmin = ((lane & k) == 0) == ((lane & j) == 0);
            v = ((v < o) == keepmin) ? v : o;
        }
    return v;
}

// pts4[b][n] = {x, y, z, ||p||^2}; norm = (z*z + y*y) + x*x desc no-FMA [verified R8]
__global__ void pack_kernel(const float* __restrict__ pts, float4* __restrict__ pts4) {
    int t = blockIdx.x * blockDim.x + threadIdx.x;
    if (t >= B * N) return;
    int b = t >> 13, n = t & (N - 1);
    const float* P = pts + (size_t)b * 3 * N;
    float x = P[n], y = P[N + n], z = P[2 * N + n];
    float pn = __fadd_rn(__fadd_rn(__fmul_rn(z, z), __fmul_rn(y, y)), __fmul_rn(x, x));
    pts4[t] = make_float4(x, y, z, pn);
}

// feat [B][D][N] -> featT [B][N][D], LDS-tiled 64x64
__global__ void __launch_bounds__(256) transpose_kernel(const float* __restrict__ feat,
                                                        float* __restrict__ featT) {
    __shared__ float tile[64][65];
    int b = blockIdx.x >> 7;
    int n0 = (blockIdx.x & 127) << 6;
    int col = threadIdx.x & 63;
    int crow = threadIdx.x >> 6;
    const float* F = feat + (size_t)b * D * N;
#pragma unroll
    for (int i = 0; i < 16; ++i) {
        int c = i * 4 + crow;
        tile[c][col] = F[(size_t)c * N + n0 + col];
    }
    __syncthreads();
    float* FT = featT + ((size_t)b * N + n0) * D;
#pragma unroll
    for (int i = 0; i < 16; ++i) {
        int nl = i * 4 + crow;
        FT[(size_t)nl * D + col] = tile[col][nl];
    }
}

// One wave per G=8 queries, two-pass threshold selection (R12 structure).
// Each point load now serves 8 queries (memory traffic halved vs G=4).
// Pass 1: per-lane min of FUSED vt; tau_d = rn(tau_vt + qn) + 1e-4 bounds the
// 16th distance. Pass 2: prefilter vt <= vthr, hits recompute EXACT v,d, check
// d <= tau_d; LDS-atomic compact; exact (d,idx) u64 bitonic sort (tie->low idx).
__global__ void __launch_bounds__(256) knn_kernel(const float4* __restrict__ pts4,
                                                  const float* __restrict__ newp,
                                                  int* __restrict__ ind) {
    __shared__ unsigned long long buf[4][G][64];
    __shared__ int cnt_lds[4][G];
    int wib = threadIdx.x >> 6;
    int lane = threadIdx.x & 63;
    int wid = blockIdx.x * 4 + wib;   // 0 .. B*S/G - 1 (2048)
    int b = wid >> 8;                 // S/G = 256 groups per batch
    int sbase = (wid & 255) * G;
    const float4* P4 = pts4 + (size_t)b * N;
    const float* Q = newp + (size_t)b * 3 * S;
    if (lane < G) cnt_lds[wib][lane] = 0;
    float qn[G], nq2x[G], nq2y[G], nq2z[G];
#pragma unroll
    for (int g = 0; g < G; ++g) {
        int s = sbase + g;
        float qx = uload(Q + s), qy = uload(Q + S + s), qz = uload(Q + 2 * S + s);
        qn[g] = __fadd_rn(__fadd_rn(__fmul_rn(qz, qz), __fmul_rn(qy, qy)), __fmul_rn(qx, qx));
        nq2x[g] = -2.0f * qx;  // exact pow-2 scale + exact negation
        nq2y[g] = -2.0f * qy;
        nq2z[g] = -2.0f * qz;
    }

    // ---- pass 1: per-lane min of fused vt over 128 candidates ----
    float m[G];
#pragma unroll
    for (int g = 0; g < G; ++g) m[g] = __int_as_float(0x7f800000);
    for (int blk = 0; blk < N / 256; ++blk) {
        int nb = blk * 256 + lane;
        float4 c0 = P4[nb], c1 = P4[nb + 64], c2 = P4[nb + 128], c3 = P4[nb + 192];
#pragma unroll
        for (int g = 0; g < G; ++g) {
            float v0 = make_vt(c0.x, c0.y, c0.z, c0.w, nq2x[g], nq2y[g], nq2z[g]);
            float v1 = make_vt(c1.x, c1.y, c1.z, c1.w, nq2x[g], nq2y[g], nq2z[g]);
            float v2 = make_vt(c2.x, c2.y, c2.z, c2.w, nq2x[g], nq2y[g], nq2z[g]);
            float v3 = make_vt(c3.x, c3.y, c3.z, c3.w, nq2x[g], nq2y[g], nq2z[g]);
            m[g] = fminf(m[g], fminf(fminf(v0, v1), fminf(v2, v3)));
        }
    }
    float tau_d[G], vthr[G];
#pragma unroll
    for (int g = 0; g < G; ++g) {
        float tau_vt = __shfl(bitonic_sort64_f32(m[g], lane), 15, 64);
        tau_d[g] = __fadd_rn(__fadd_rn(tau_vt, qn[g]), 1e-4f);  // >= 16th distance
        vthr[g] = __fadd_rn(__fsub_rn(tau_d[g], qn[g]), 1e-4f); // superset prefilter on vt
    }

    // ---- pass 2: prefilter on fused vt; hits do exact v,d + atomic compact ----
    for (int blk = 0; blk < N / 256; ++blk) {
        int nb = blk * 256 + lane;
        float4 cc[4] = {P4[nb], P4[nb + 64], P4[nb + 128], P4[nb + 192]};
#pragma unroll
        for (int g = 0; g < G; ++g) {
#pragma unroll
            for (int i = 0; i < 4; ++i) {
                float vt = make_vt(cc[i].x, cc[i].y, cc[i].z, cc[i].w, nq2x[g], nq2y[g], nq2z[g]);
                if (vt <= vthr[g]) {  // rare divergent branch
                    // exact reference arithmetic on the hit
                    float v = make_v(cc[i].x, cc[i].y, cc[i].z, cc[i].w,
                                     -nq2x[g], -nq2y[g], -nq2z[g]);
                    float d = __fadd_rn(v, qn[g]);
                    if (d <= tau_d[g]) {
                        int pos = atomicAdd(&cnt_lds[wib][g], 1);
                        if (pos < 64)
                            buf[wib][g][pos] =
                                ((unsigned long long)sortable(d) << 32) | (unsigned)(nb + i * 64);
                    }
                }
            }
        }
    }
    __syncthreads();

#pragma unroll
    for (int g = 0; g < G; ++g) {
        int cnt = cnt_lds[wib][g];
        int* my_ind = ind + ((size_t)b * S + sbase + g) * K;
        if (cnt <= 64) {
            unsigned long long key = (lane < cnt) ? buf[wib][g][lane] : ~0ull;
            key = bitonic_sort64_u64(key, lane);
            if (lane < K) my_ind[lane] = (int)(unsigned)key;
        } else {
            // Exact fallback (never expected on random data)
            float qx = -0.5f * nq2x[g], qy = -0.5f * nq2y[g], qz = -0.5f * nq2z[g];
            unsigned long long a[K];
#pragma unroll
            for (int i = 0; i < K; ++i) a[i] = ~0ull;
            for (int n = lane; n < N; n += 64) {
                float4 c = P4[n];
                float d = make_d(c.x, c.y, c.z, c.w, qx, qy, qz, qn[g]);
                unsigned long long key = ((unsigned long long)sortable(d) << 32) | (unsigned)n;
                if (key < a[K - 1]) {
#pragma unroll
                    for (int i = K - 1; i >= 1; --i) {
                        unsigned long long lo = a[i - 1];
                        a[i] = key < lo ? lo : (key < a[i] ? key : a[i]);
                    }
                    a[0] = key < a[0] ? key : a[0];
                }
            }
            for (int r = 0; r < K; ++r) {
                unsigned long long best = a[0];
#pragma unroll
                for (int mm = 1; mm < 64; mm <<= 1) {
                    unsigned long long o = __shfl_xor(best, mm, 64);
                    best = o < best ? o : best;
                }
                if (lane == 0) my_ind[r] = (int)(unsigned)best;
                bool won = (a[0] == best);
#pragma unroll
                for (int i = 0; i < K - 1; ++i) a[i] = won ? a[i + 1] : a[i];
                a[K - 1] = won ? ~0ull : a[K - 1];
            }
        }
    }
}

// Output [B][C][K][S]. t -> (b, g, k, s); g=0: 3 coord channels from pts4;
// g=1..16: 4 feat channels via one float4 from featT (or 4 scalar loads).
__global__ void __launch_bounds__(256) gather_kernel(const float4* __restrict__ pts4,
                                                     const float* __restrict__ newp,
                                                     const float* __restrict__ feat,
                                                     const float* __restrict__ featT,
                                                     const int* __restrict__ ind,
                                                     float* __restrict__ out, int useT) {
    int t = blockIdx.x * blockDim.x + threadIdx.x;
    int s = t & (S - 1);
    int k = (t >> 11) & (K - 1);
    int rest = t >> 15;
    int g = rest % 17;
    int b = rest / 17;
    if (b >= B) return;
    int id = ind[((size_t)b * S + s) * K + k];
    size_t KS = (size_t)K * S;
    if (g == 0) {
        float4 p = pts4[(size_t)b * N + id];
        const float* Q = newp + (size_t)b * 3 * S;
        float* o = out + ((size_t)b * C * K + k) * S + s;
        o[0] = __fsub_rn(p.x, Q[s]);
        o[KS] = __fsub_rn(p.y, Q[S + s]);
        o[2 * KS] = __fsub_rn(p.z, Q[2 * S + s]);
    } else {
        int cb = (g - 1) * 4;
        float4 f;
        if (useT) {
            f = *(const float4*)(featT + ((size_t)b * N + id) * D + cb);
        } else {
            const float* F = feat + (size_t)b * D * N;
            f = make_float4(F[(size_t)cb * N + id], F[(size_t)(cb + 1) * N + id],
                            F[(size_t)(cb + 2) * N + id], F[(size_t)(cb + 3) * N + id]);
        }
        float* o = out + (((size_t)b * C + 3 + cb) * K + k) * S + s;
        o[0] = f.x;
        o[KS] = f.y;
        o[2 * KS] = f.z;
        o[3 * KS] = f.w;
    }
}

extern "C" void kernel_launch(void* const* d_in, const int* in_sizes, int n_in,
                              void* d_out, int out_size, void* d_ws, size_t ws_size,
                              hipStream_t stream) {
    const float* pts = (const float*)d_in[0];   // [B, 3, N]
    const float* newp = (const float*)d_in[1];  // [B, 3, S]
    const float* feat = (const float*)d_in[2];  // [B, D, N]
    float* out = (float*)d_out;                 // [B, C, K, S]

    size_t off_ind = 0;
    size_t off_pts4 = (size_t)B * S * K * sizeof(int);              // 2 MB
    size_t off_featT = off_pts4 + (size_t)B * N * sizeof(float4);   // +1 MB
    size_t need = off_featT + (size_t)B * N * D * sizeof(float);    // +16 MB
    int* ind = (int*)((char*)d_ws + off_ind);
    float4* pts4 = (float4*)((char*)d_ws + off_pts4);
    float* featT = (float*)((char*)d_ws + off_featT);
    int useT = (ws_size >= need) ? 1 : 0;

    pack_kernel<<<(B * N) / 256, 256, 0, stream>>>(pts, pts4);
    if (useT) transpose_kernel<<<B * (N / 64), 256, 0, stream>>>(feat, featT);
    knn_kernel<<<(B * S) / (G * 4), 256, 0, stream>>>(pts4, newp, ind);
    gather_kernel<<<(B * 17 * K * S) / 256, 256, 0, stream>>>(pts4, newp, feat, featT, ind, out, useT);
}

// Round 17
// 91.785 us; speedup vs baseline: 1.5310x; 1.5310x over previous
//
#include <hip/hip_runtime.h>

constexpr int B = 8, N = 8192, S = 2048, D = 64, K = 16, C = 3 + D;
constexpr int G = 4;  // queries per wave (R12-verified structure)

// Map float -> monotonically sortable unsigned (total order matches float <)
__device__ __forceinline__ unsigned sortable(float f) {
    unsigned u = __float_as_uint(f);
    unsigned mask = (unsigned)(((int)u) >> 31) | 0x80000000u;
    return u ^ mask;
}

// Wave-uniform load -> SGPR
__device__ __forceinline__ float uload(const float* p) {
    return __uint_as_float(__builtin_amdgcn_readfirstlane(__float_as_uint(*p)));
}

// Scalar reference-exact distance (fallback path): dot asc-FMA, d=(pn-2dot)+qn [R8]
__device__ __forceinline__ float make_d(float px, float py, float pz, float pnv,
                                        float qx, float qy, float qz, float qn) {
    float dot = __fmaf_rn(pz, qz, __fmaf_rn(py, qy, __fmul_rn(px, qx)));
    return __fadd_rn(__fsub_rn(pnv, __fmul_rn(2.0f, dot)), qn);
}

// EXACT v = pn - dot2; dot2 = fma(pz,q2z, fma(py,q2y, px*q2x)) == 2*dot bitwise
__device__ __forceinline__ float make_v(float px, float py, float pz, float pnv,
                                        float q2x, float q2y, float q2z) {
    float dot2 = __fmaf_rn(pz, q2z, __fmaf_rn(py, q2y, __fmul_rn(px, q2x)));
    return __fsub_rn(pnv, dot2);
}

__device__ __forceinline__ float bitonic_sort64_f32(float v, int lane) {
#pragma unroll
    for (int k = 2; k <= 64; k <<= 1)
#pragma unroll
        for (int j = k >> 1; j > 0; j >>= 1) {
            float o = __shfl_xor(v, j, 64);
            bool keepmin = ((lane & k) == 0) == ((lane & j) == 0);
            float mn = fminf(v, o), mx = fmaxf(v, o);
            v = keepmin ? mn : mx;
        }
    return v;
}

__device__ __forceinline__ unsigned long long bitonic_sort64_u64(unsigned long long v, int lane) {
#pragma unroll
    for (int k = 2; k <= 64; k <<= 1)
#pragma unroll
        for (int j = k >> 1; j > 0; j >>= 1) {
            unsigned long long o = __shfl_xor(v, j, 64);
            bool keepmin = ((lane & k) == 0) == ((lane & j) == 0);
            v = ((v < o) == keepmin) ? v : o;
        }
    return v;
}

// pts4[b][n] = {x, y, z, ||p||^2}; norm = (z*z + y*y) + x*x desc no-FMA [verified R8]
__global__ void pack_kernel(const float* __restrict__ pts, float4* __restrict__ pts4) {
    int t = blockIdx.x * blockDim.x + threadIdx.x;
    if (t >= B * N) return;
    int b = t >> 13, n = t & (N - 1);
    const float* P = pts + (size_t)b * 3 * N;
    float x = P[n], y = P[N + n], z = P[2 * N + n];
    float pn = __fadd_rn(__fadd_rn(__fmul_rn(z, z), __fmul_rn(y, y)), __fmul_rn(x, x));
    pts4[t] = make_float4(x, y, z, pn);
}

// feat [B][D][N] -> featT [B][N][D], LDS-tiled 64x64
__global__ void __launch_bounds__(256) transpose_kernel(const float* __restrict__ feat,
                                                        float* __restrict__ featT) {
    __shared__ float tile[64][65];
    int b = blockIdx.x >> 7;
    int n0 = (blockIdx.x & 127) << 6;
    int col = threadIdx.x & 63;
    int crow = threadIdx.x >> 6;
    const float* F = feat + (size_t)b * D * N;
#pragma unroll
    for (int i = 0; i < 16; ++i) {
        int c = i * 4 + crow;
        tile[c][col] = F[(size_t)c * N + n0 + col];
    }
    __syncthreads();
    float* FT = featT + ((size_t)b * N + n0) * D;
#pragma unroll
    for (int i = 0; i < 16; ++i) {
        int nl = i * 4 + crow;
        FT[(size_t)nl * D + col] = tile[col][nl];
    }
}

// ===== knn: exact R12 structure (62 us floor, converged) =====
__global__ void __launch_bounds__(256) knn_kernel(const float4* __restrict__ pts4,
                                                  const float* __restrict__ newp,
                                                  int* __restrict__ ind) {
    __shared__ unsigned long long buf[4][G][64];
    __shared__ int cnt_lds[4][G];
    int wib = threadIdx.x >> 6;
    int lane = threadIdx.x & 63;
    int wid = blockIdx.x * 4 + wib;
    int b = wid >> 9;
    int sbase = (wid & 511) * G;
    const float4* P4 = pts4 + (size_t)b * N;
    const float* Q = newp + (size_t)b * 3 * S;
    if (lane < G) cnt_lds[wib][lane] = 0;
    float qx[G], qy[G], qz[G], qn[G], q2x[G], q2y[G], q2z[G];
#pragma unroll
    for (int g = 0; g < G; ++g) {
        int s = sbase + g;
        qx[g] = uload(Q + s);
        qy[g] = uload(Q + S + s);
        qz[g] = uload(Q + 2 * S + s);
        qn[g] = __fadd_rn(__fadd_rn(__fmul_rn(qz[g], qz[g]), __fmul_rn(qy[g], qy[g])),
                          __fmul_rn(qx[g], qx[g]));
        q2x[g] = 2.0f * qx[g];  // exact pow-2 scale
        q2y[g] = 2.0f * qy[g];
        q2z[g] = 2.0f * qz[g];
    }

    // ---- pass 1: per-lane min of v over 128 candidates ----
    float m[G];
#pragma unroll
    for (int g = 0; g < G; ++g) m[g] = __int_as_float(0x7f800000);
    for (int blk = 0; blk < N / 256; ++blk) {
        int nb = blk * 256 + lane;
        float4 c0 = P4[nb], c1 = P4[nb + 64], c2 = P4[nb + 128], c3 = P4[nb + 192];
#pragma unroll
        for (int g = 0; g < G; ++g) {
            float v0 = make_v(c0.x, c0.y, c0.z, c0.w, q2x[g], q2y[g], q2z[g]);
            float v1 = make_v(c1.x, c1.y, c1.z, c1.w, q2x[g], q2y[g], q2z[g]);
            float v2 = make_v(c2.x, c2.y, c2.z, c2.w, q2x[g], q2y[g], q2z[g]);
            float v3 = make_v(c3.x, c3.y, c3.z, c3.w, q2x[g], q2y[g], q2z[g]);
            m[g] = fminf(m[g], fminf(fminf(v0, v1), fminf(v2, v3)));
        }
    }
    float tau_d[G], vthr[G];
#pragma unroll
    for (int g = 0; g < G; ++g) {
        float tau_v = __shfl(bitonic_sort64_f32(m[g], lane), 15, 64);
        tau_d[g] = __fadd_rn(tau_v, qn[g]);  // valid upper bound on 16th distance
        vthr[g] = __fadd_rn(__fsub_rn(tau_d[g], qn[g]), 1e-4f);  // superset pre-filter
    }

    // ---- pass 2: pre-filter on v, exact check + LDS-atomic compact ----
    for (int blk = 0; blk < N / 256; ++blk) {
        int nb = blk * 256 + lane;
        float4 c0 = P4[nb], c1 = P4[nb + 64], c2 = P4[nb + 128], c3 = P4[nb + 192];
#pragma unroll
        for (int g = 0; g < G; ++g) {
            float vv[4];
            vv[0] = make_v(c0.x, c0.y, c0.z, c0.w, q2x[g], q2y[g], q2z[g]);
            vv[1] = make_v(c1.x, c1.y, c1.z, c1.w, q2x[g], q2y[g], q2z[g]);
            vv[2] = make_v(c2.x, c2.y, c2.z, c2.w, q2x[g], q2y[g], q2z[g]);
            vv[3] = make_v(c3.x, c3.y, c3.z, c3.w, q2x[g], q2y[g], q2z[g]);
#pragma unroll
            for (int i = 0; i < 4; ++i) {
                if (vv[i] <= vthr[g]) {  // rare divergent branch
                    float d = __fadd_rn(vv[i], qn[g]);  // exact reference d
                    if (d <= tau_d[g]) {
                        int pos = atomicAdd(&cnt_lds[wib][g], 1);
                        if (pos < 64)
                            buf[wib][g][pos] =
                                ((unsigned long long)sortable(d) << 32) | (unsigned)(nb + i * 64);
                    }
                }
            }
        }
    }
    __syncthreads();

#pragma unroll
    for (int g = 0; g < G; ++g) {
        int cnt = cnt_lds[wib][g];
        int* my_ind = ind + ((size_t)b * S + sbase + g) * K;
        if (cnt <= 64) {
            unsigned long long key = (lane < cnt) ? buf[wib][g][lane] : ~0ull;
            key = bitonic_sort64_u64(key, lane);
            if (lane < K) my_ind[lane] = (int)(unsigned)key;
        } else {
            // Exact fallback (never expected on random data)
            unsigned long long a[K];
#pragma unroll
            for (int i = 0; i < K; ++i) a[i] = ~0ull;
            for (int n = lane; n < N; n += 64) {
                float4 c = P4[n];
                float d = make_d(c.x, c.y, c.z, c.w, qx[g], qy[g], qz[g], qn[g]);
                unsigned long long key = ((unsigned long long)sortable(d) << 32) | (unsigned)n;
                if (key < a[K - 1]) {
#pragma unroll
                    for (int i = K - 1; i >= 1; --i) {
                        unsigned long long lo = a[i - 1];
                        a[i] = key < lo ? lo : (key < a[i] ? key : a[i]);
                    }
                    a[0] = key < a[0] ? key : a[0];
                }
            }
            for (int r = 0; r < K; ++r) {
                unsigned long long best = a[0];
#pragma unroll
                for (int mm = 1; mm < 64; mm <<= 1) {
                    unsigned long long o = __shfl_xor(best, mm, 64);
                    best = o < best ? o : best;
                }
                if (lane == 0) my_ind[r] = (int)(unsigned)best;
                bool won = (a[0] == best);
#pragma unroll
                for (int i = 0; i < K - 1; ++i) a[i] = won ? a[i + 1] : a[i];
                a[K - 1] = won ? ~0ull : a[K - 1];
            }
        }
    }
}

// ===== gather: LDS-staged tile. Block = (b, k, 64-s tile). =====
// Phase 1: 4 lanes per neighbor read the full 256B featT row (4-lane-contiguous
// 64B segments -> 16 line-transactions per wave-load) + coords; stage in LDS
// tile[64 s][69 pad]. Phase 2: coalesced 256B stores per (c, s-run).
__global__ void __launch_bounds__(256) gather_tile_kernel(const float4* __restrict__ pts4,
                                                          const float* __restrict__ newp,
                                                          const float* __restrict__ featT,
                                                          const int* __restrict__ ind,
                                                          float* __restrict__ out) {
    __shared__ float tile[64][69];  // odd stride: phase-2 reads <=2-way bank alias
    int bid = blockIdx.x;           // b*(K*32) + k*32 + st
    int b = bid >> 9;               // K*32 = 512
    int k = (bid >> 5) & (K - 1);
    int s0 = (bid & 31) << 6;
    int j = threadIdx.x >> 2;  // neighbor (s-lane) 0..63
    int p = threadIdx.x & 3;   // row piece 0..3
    int s = s0 + j;
    int id = ind[((size_t)b * S + s) * K + k];
    const float* row = featT + ((size_t)b * N + id) * D;
    // feature channels: piece p covers float4 indices {p, p+4, p+8, p+12}
#pragma unroll
    for (int i = 0; i < 4; ++i) {
        int f = p + 4 * i;
        float4 v = *(const float4*)(row + f * 4);
        *(float4*)(&tile[j][3 + f * 4]) = v;  // unaligned-in-LDS ok? -> scalar fallback below
    }
    // coords (p==0 lanes only): tile[j][0..2] = pts4[id].xyz - newp[b][*][s]
    if (p == 0) {
        float4 pt = pts4[(size_t)b * N + id];
        const float* Q = newp + (size_t)b * 3 * S;
        tile[j][0] = __fsub_rn(pt.x, Q[s]);
        tile[j][1] = __fsub_rn(pt.y, Q[S + s]);
        tile[j][2] = __fsub_rn(pt.z, Q[2 * S + s]);
    }
    __syncthreads();
    // phase 2: 4 channels x 64 s per iteration, 17 iterations (68 slots, 67 used)
    size_t KS = (size_t)K * S;
    float* ob = out + ((size_t)b * C * K + k) * S + s0;
#pragma unroll
    for (int it = 0; it < 17; ++it) {
        int c = it * 4 + (threadIdx.x >> 6);
        int l = threadIdx.x & 63;
        if (c < C) ob[(size_t)c * KS + l] = tile[l][c];
    }
}

// Fallback gather (no featT workspace): per-thread reads from channel-major feat.
__global__ void __launch_bounds__(256) gather_kernel(const float4* __restrict__ pts4,
                                                     const float* __restrict__ newp,
                                                     const float* __restrict__ feat,
                                                     const int* __restrict__ ind,
                                                     float* __restrict__ out) {
    int t = blockIdx.x * blockDim.x + threadIdx.x;
    int s = t & (S - 1);
    int k = (t >> 11) & (K - 1);
    int rest = t >> 15;
    int g = rest % 17;
    int b = rest / 17;
    if (b >= B) return;
    int id = ind[((size_t)b * S + s) * K + k];
    size_t KS = (size_t)K * S;
    if (g == 0) {
        float4 p = pts4[(size_t)b * N + id];
        const float* Q = newp + (size_t)b * 3 * S;
        float* o = out + ((size_t)b * C * K + k) * S + s;
        o[0] = __fsub_rn(p.x, Q[s]);
        o[KS] = __fsub_rn(p.y, Q[S + s]);
        o[2 * KS] = __fsub_rn(p.z, Q[2 * S + s]);
    } else {
        int cb = (g - 1) * 4;
        const float* F = feat + (size_t)b * D * N;
        float4 f = make_float4(F[(size_t)cb * N + id], F[(size_t)(cb + 1) * N + id],
                               F[(size_t)(cb + 2) * N + id], F[(size_t)(cb + 3) * N + id]);
        float* o = out + (((size_t)b * C + 3 + cb) * K + k) * S + s;
        o[0] = f.x;
        o[KS] = f.y;
        o[2 * KS] = f.z;
        o[3 * KS] = f.w;
    }
}

extern "C" void kernel_launch(void* const* d_in, const int* in_sizes, int n_in,
                              void* d_out, int out_size, void* d_ws, size_t ws_size,
                              hipStream_t stream) {
    const float* pts = (const float*)d_in[0];   // [B, 3, N]
    const float* newp = (const float*)d_in[1];  // [B, 3, S]
    const float* feat = (const float*)d_in[2];  // [B, D, N]
    float* out = (float*)d_out;                 // [B, C, K, S]

    size_t off_ind = 0;
    size_t off_pts4 = (size_t)B * S * K * sizeof(int);              // 2 MB
    size_t off_featT = off_pts4 + (size_t)B * N * sizeof(float4);   // +1 MB
    size_t need = off_featT + (size_t)B * N * D * sizeof(float);    // +16 MB
    int* ind = (int*)((char*)d_ws + off_ind);
    float4* pts4 = (float4*)((char*)d_ws + off_pts4);
    float* featT = (float*)((char*)d_ws + off_featT);
    int useT = (ws_size >= need) ? 1 : 0;

    pack_kernel<<<(B * N) / 256, 256, 0, stream>>>(pts, pts4);
    if (useT) transpose_kernel<<<B * (N / 64), 256, 0, stream>>>(feat, featT);
    knn_kernel<<<(B * S) / (G * 4), 256, 0, stream>>>(pts4, newp, ind);
    if (useT)
        gather_tile_kernel<<<B * K * (S / 64), 256, 0, stream>>>(pts4, newp, featT, ind, out);
    else
        gather_kernel<<<(B * 17 * K * S) / 256, 256, 0, stream>>>(pts4, newp, feat, ind, out);
}